// Round 4
// baseline (171.890 us; speedup 1.0000x reference)
//
#include <hip/hip_runtime.h>

// R-GCN layer: out[n] = rsqrt(in_deg[n]) * sum_{e: dst=n} W[order[e]] @ (feat[src[e]] * rsqrt(out_deg[src[e]])) + bias
// R4: k_edge drops LDS entirely — edge (src,dst) pairs are pre-scattered into a
// relation-sorted int2 array (one coalesced load per 64 edges), per-edge indices
// extracted via __shfl (uniform -> readlane/SGPR), so the h row loads are
// wave-uniform broadcasts with no LDS round-trip. Contiguous per-wave chunks.
// d_out zeroing fused into k_prep (6 -> 5 graph ops).

constexpr int N_NODES = 10000;
constexpr int N_EDGES = 100000;
constexpr int F = 64;           // in = out feats
constexpr int R = 10;           // edge types
constexpr int BLOCK = 256;
constexpr int WPB = BLOCK / 64;
constexpr int EDGE_BLOCKS = 1024;
constexpr int G_WAVES = EDGE_BLOCKS * WPB;  // 4096

__global__ void k_count(const int* __restrict__ src, const int* __restrict__ dst,
                        const int* __restrict__ order,
                        int* deg_out, int* deg_in, int* rel_cnt, int* rank,
                        int* done, int* rel_off, int* rel_woff) {
    __shared__ int hist[R], base[R];
    int tid = threadIdx.x;
    int e = blockIdx.x * BLOCK + tid;
    if (tid < R) hist[tid] = 0;
    __syncthreads();
    int r = -1, lr = 0;
    if (e < N_EDGES) {
        atomicAdd(&deg_out[src[e]], 1);      // native int atomic, fire-and-forget
        atomicAdd(&deg_in[dst[e]], 1);
        r = order[e];
        lr = atomicAdd(&hist[r], 1);         // LDS atomic: intra-block rank
    }
    __syncthreads();
    if (tid < R) base[tid] = hist[tid] ? atomicAdd(&rel_cnt[tid], hist[tid]) : 0;
    __syncthreads();
    if (e < N_EDGES) rank[e] = base[r] + lr;

    // fused scan: last block to finish computes rel_off / rel_woff
    if (tid == 0) {
        __threadfence();
        if (atomicAdd(done, 1) == (int)gridDim.x - 1) {
            int off = 0;
            for (int rr = 0; rr < R; ++rr) {
                int c = atomicAdd(&rel_cnt[rr], 0);   // coherent read
                rel_off[rr] = off; off += c;
            }
            rel_off[R] = off;                          // == N_EDGES
            for (int rr = 0; rr <= R; ++rr)
                rel_woff[rr] = (int)((long long)rel_off[rr] * G_WAVES / N_EDGES);
        }
    }
}

// scatter relation-sorted (src,dst) pairs + featn = feat * rsqrt(out_deg) + zero out
__global__ void k_prep(const int* __restrict__ src, const int* __restrict__ dst,
                       const int* __restrict__ order, const int* __restrict__ rank,
                       const int* __restrict__ rel_off, const int* __restrict__ deg_out,
                       const float* __restrict__ feat,
                       int2* __restrict__ sd, float* __restrict__ featn,
                       float* __restrict__ out) {
    int t = blockIdx.x * BLOCK + threadIdx.x;
    if (t < N_NODES * F) {
        featn[t] = feat[t] * rsqrtf((float)max(deg_out[t >> 6], 1));
        out[t] = 0.0f;                       // harness poisons d_out; atomics need zeros
    }
    if (t < N_EDGES)
        sd[rel_off[order[t]] + rank[t]] = make_int2(src[t], dst[t]);
}

__global__ __launch_bounds__(BLOCK) void k_edge(
    const float* __restrict__ featn, const float* __restrict__ emb,
    const int* __restrict__ rel_off, const int* __restrict__ rel_woff,
    const int2* __restrict__ sd, float* __restrict__ out) {
    int lane = threadIdx.x & 63;
    int wib = threadIdx.x >> 6;
    int g = blockIdx.x * WPB + wib;

    for (int r = 0; r < R; ++r) {
        int w0 = rel_woff[r], w1 = rel_woff[r + 1];
        int nw = w1 - w0;
        int e0 = rel_off[r], cnt = rel_off[r + 1] - e0;
        int a, b;
        if (nw == 0) {               // tiny bucket got 0 waves: boundary wave covers it alone
            if (g != w0 || cnt == 0) continue;
            a = e0; b = e0 + cnt;
        } else {
            if (g < w0 || g >= w1) continue;
            int lw = g - w0;
            a = e0 + (int)((long long)cnt * lw / nw);
            b = e0 + (int)((long long)cnt * (lw + 1) / nw);
        }
        if (a >= b) continue;

        // This relation's W: lane o holds row o (64 floats) in VGPRs, pinned.
        float wreg[F];
        const float4* wr4 = (const float4*)(emb + (size_t)r * F * F + (size_t)lane * F);
#pragma unroll
        for (int k4 = 0; k4 < F / 4; ++k4) {
            float4 t = wr4[k4];
            wreg[4 * k4 + 0] = t.x; wreg[4 * k4 + 1] = t.y;
            wreg[4 * k4 + 2] = t.z; wreg[4 * k4 + 3] = t.w;
        }
#pragma unroll
        for (int i = 0; i < F; ++i) asm volatile("" : "+v"(wreg[i]));

        for (int base = a; base < b; base += 64) {
            int n = min(64, b - base);
            int2 m = make_int2(0, 0);
            if (base + lane < b) m = sd[base + lane];   // ONE coalesced 512B load / 64 edges

            for (int j = 0; j < n; j += 2) {
                bool hasB = (j + 1) < n;
                int jB = hasB ? j + 1 : j;
                int sA = __shfl(m.x, j),  dA = __shfl(m.y, j);    // uniform -> SGPR
                int sB = __shfl(m.x, jB), dB = __shfl(m.y, jB);
                const float4* rA = (const float4*)featn + ((size_t)sA << 4);
                const float4* rB = (const float4*)featn + ((size_t)sB << 4);
                float a0 = 0.f, a1 = 0.f, b0 = 0.f, b1 = 0.f;     // 4 indep FMA chains
#pragma unroll
                for (int k4 = 0; k4 < 16; k4 += 2) {
                    float4 va  = rA[k4];        // wave-uniform broadcast loads
                    float4 va2 = rA[k4 + 1];
                    float4 vb  = rB[k4];
                    float4 vb2 = rB[k4 + 1];
                    a0 = fmaf(wreg[4 * k4 + 0], va.x, a0);
                    a0 = fmaf(wreg[4 * k4 + 1], va.y, a0);
                    a0 = fmaf(wreg[4 * k4 + 2], va.z, a0);
                    a0 = fmaf(wreg[4 * k4 + 3], va.w, a0);
                    a1 = fmaf(wreg[4 * k4 + 4], va2.x, a1);
                    a1 = fmaf(wreg[4 * k4 + 5], va2.y, a1);
                    a1 = fmaf(wreg[4 * k4 + 6], va2.z, a1);
                    a1 = fmaf(wreg[4 * k4 + 7], va2.w, a1);
                    b0 = fmaf(wreg[4 * k4 + 0], vb.x, b0);
                    b0 = fmaf(wreg[4 * k4 + 1], vb.y, b0);
                    b0 = fmaf(wreg[4 * k4 + 2], vb.z, b0);
                    b0 = fmaf(wreg[4 * k4 + 3], vb.w, b0);
                    b1 = fmaf(wreg[4 * k4 + 4], vb2.x, b1);
                    b1 = fmaf(wreg[4 * k4 + 5], vb2.y, b1);
                    b1 = fmaf(wreg[4 * k4 + 6], vb2.z, b1);
                    b1 = fmaf(wreg[4 * k4 + 7], vb2.w, b1);
                }
                // HW fp32 atomic, wave-contiguous 256B
                unsafeAtomicAdd(&out[((size_t)dA << 6) + lane], a0 + a1);
                if (hasB) unsafeAtomicAdd(&out[((size_t)dB << 6) + lane], b0 + b1);
            }
        }
    }
}

__global__ void k_final(const int* __restrict__ deg_in, const float* __restrict__ bias,
                        float* __restrict__ out) {
    int t = blockIdx.x * BLOCK + threadIdx.x;     // indexes float4
    if (t < N_NODES * F / 4) {
        int n = t >> 4, o4 = t & 15;
        float s = rsqrtf((float)max(deg_in[n], 1));
        float4 v = ((float4*)out)[t];
        float4 b = ((const float4*)bias)[o4];
        v.x = v.x * s + b.x; v.y = v.y * s + b.y;
        v.z = v.z * s + b.z; v.w = v.w * s + b.w;
        ((float4*)out)[t] = v;
    }
}

extern "C" void kernel_launch(void* const* d_in, const int* in_sizes, int n_in,
                              void* d_out, int out_size, void* d_ws, size_t ws_size,
                              hipStream_t stream) {
    const float* feat  = (const float*)d_in[0];
    const int*   src   = (const int*)d_in[1];
    const int*   dst   = (const int*)d_in[2];
    const int*   order = (const int*)d_in[3];
    const float* emb   = (const float*)d_in[4];
    const float* bias  = (const float*)d_in[5];
    float* out = (float*)d_out;

    // Workspace layout
    int*   deg_out  = (int*)d_ws;                // N_NODES
    int*   deg_in   = deg_out + N_NODES;         // N_NODES
    int*   rel_cnt  = deg_in + N_NODES;          // 16
    int*   done     = rel_cnt + 16;              // 16
    int*   rel_off  = done + 16;                 // 16 (11 used)
    int*   rel_woff = rel_off + 16;              // 16 (11 used)
    int*   rank     = rel_woff + 16;             // N_EDGES
    int2*  sd       = (int2*)(rank + N_EDGES);   // N_EDGES int2 (8B-aligned: offset even)
    float* featn    = (float*)(sd + N_EDGES);    // N_NODES*F

    size_t zbytes = (size_t)(2 * N_NODES + 32) * sizeof(int);  // deg arrays + rel_cnt + done
    hipMemsetAsync(d_ws, 0, zbytes, stream);

    int eb = (N_EDGES + BLOCK - 1) / BLOCK;
    k_count<<<eb, BLOCK, 0, stream>>>(src, dst, order, deg_out, deg_in,
                                      rel_cnt, rank, done, rel_off, rel_woff);
    int pb = (N_NODES * F + BLOCK - 1) / BLOCK;
    k_prep<<<pb, BLOCK, 0, stream>>>(src, dst, order, rank, rel_off, deg_out,
                                     feat, sd, featn, out);
    k_edge<<<EDGE_BLOCKS, BLOCK, 0, stream>>>(featn, emb, rel_off, rel_woff, sd, out);
    k_final<<<(N_NODES * F / 4 + BLOCK - 1) / BLOCK, BLOCK, 0, stream>>>(deg_in, bias, out);
}